// Round 8
// baseline (566.275 us; speedup 1.0000x reference)
//
#include <hip/hip_runtime.h>
#include <hip/hip_bf16.h>

// SectorGCN R8: R7 + non-temporal hints on all streaming traffic so the hot
// random arrays (hdb 3.2MB, qb 200KB) stay resident in each XCD's 4MB L2,
// + unroll x8 in gather1 for deeper memory-level parallelism.
// N=100000, E=3200000, d_in=128, d_h=16.

#define DH 16
#define BSH 6
#define BNODES 64
#define NB_MAX 1568
#define CHUNK 4096        // scatter chunk
#define HCHUNK 8192       // hist chunk
#define NSLICE 4

typedef unsigned long long u64;

__device__ __forceinline__ u64 nt_load_u64(const uint2* p) {
    return __builtin_nontemporal_load((const u64*)p);
}

__global__ __launch_bounds__(256) void k_Ahist(const int* __restrict__ col,
                                               int* __restrict__ gCnt, int E, int NB) {
    __shared__ int lh[NB_MAX];
    const int tid = threadIdx.x;
    for (int i = tid; i < NB; i += 256) lh[i] = 0;
    __syncthreads();
    const int base = blockIdx.x * HCHUNK;
    #pragma unroll
    for (int k = 0; k < 32; ++k) {
        int e = base + tid + 256 * k;
        if (e < E) atomicAdd(&lh[__builtin_nontemporal_load(col + e) >> BSH], 1);
    }
    __syncthreads();
    for (int i = tid; i < NB; i += 256) {
        int v = lh[i];
        if (v) atomicAdd(&gCnt[i], v);
    }
}

// exclusive scan of gCnt[NB], NB <= 2048 (2 elems/thread)
__global__ __launch_bounds__(1024) void k_Ascan(const int* __restrict__ gCnt,
                                                int* __restrict__ gBase,
                                                int* __restrict__ gCursor,
                                                int NB, int E) {
    __shared__ int s[1024];
    const int t = threadIdx.x;
    const int i0 = 2 * t, i1 = 2 * t + 1;
    int a = (i0 < NB) ? gCnt[i0] : 0;
    int b = (i1 < NB) ? gCnt[i1] : 0;
    int v = a + b;
    s[t] = v;
    __syncthreads();
    for (int off = 1; off < 1024; off <<= 1) {
        int u = (t >= off) ? s[t - off] : 0;
        __syncthreads();
        s[t] += u;
        __syncthreads();
    }
    int ex = s[t] - v;
    if (i0 < NB) { gBase[i0] = ex;     gCursor[i0] = ex; }
    if (i1 < NB) { gBase[i1] = ex + a; gCursor[i1] = ex + a; }
    if (t == 0) gBase[NB] = E;
}

// LDS-staged scatter: count -> local scan -> per-(block,bucket) run
// reservation -> place sorted in LDS -> linear (coalesced-run) nt write-out.
__global__ __launch_bounds__(256) void k_Ascatter(const int* __restrict__ row,
                                                  const int* __restrict__ col,
                                                  const float* __restrict__ ew,
                                                  int* __restrict__ gCursor,
                                                  uint2* __restrict__ edata,
                                                  int E, int NB) {
    __shared__ int lh[NB_MAX];      // counts, then (globalRun - localBase)
    __shared__ int lbase[NB_MAX];
    __shared__ int lcur[NB_MAX];
    __shared__ int tsum[256];
    __shared__ unsigned short sbuck[CHUNK];
    __shared__ uint2 stage[CHUNK];  // 32 KB
    const int tid = threadIdx.x;
    for (int i = tid; i < NB; i += 256) lh[i] = 0;
    __syncthreads();
    const int base = blockIdx.x * CHUNK;
    int r_[16], c_[16];
    float w_[16];
    #pragma unroll
    for (int k = 0; k < 16; ++k) {
        int e = base + tid + 256 * k;
        bool ok = e < E;
        c_[k] = ok ? __builtin_nontemporal_load(col + e) : -1;
        r_[k] = ok ? __builtin_nontemporal_load(row + e) : 0;
        w_[k] = ok ? __builtin_nontemporal_load(ew + e) : 0.f;
        if (ok) atomicAdd(&lh[c_[k] >> BSH], 1);
    }
    __syncthreads();
    const int t0 = tid * 8;
    int c8[8];
    int mysum = 0;
    #pragma unroll
    for (int k = 0; k < 8; ++k) {
        c8[k] = (t0 + k < NB) ? lh[t0 + k] : 0;
        mysum += c8[k];
    }
    tsum[tid] = mysum;
    __syncthreads();
    for (int off = 1; off < 256; off <<= 1) {
        int u = (tid >= off) ? tsum[tid - off] : 0;
        __syncthreads();
        tsum[tid] += u;
        __syncthreads();
    }
    int p = tsum[tid] - mysum;
    #pragma unroll
    for (int k = 0; k < 8; ++k) {
        if (t0 + k < NB) { lbase[t0 + k] = p; lcur[t0 + k] = p; }
        p += c8[k];
    }
    __syncthreads();
    for (int b = tid; b < NB; b += 256) {
        int cnt = lh[b];
        if (cnt) {
            int g = atomicAdd(&gCursor[b], cnt);
            lh[b] = g - lbase[b];
        }
    }
    __syncthreads();
    #pragma unroll
    for (int k = 0; k < 16; ++k) {
        if (c_[k] >= 0) {
            int b = c_[k] >> BSH;
            unsigned rem = (unsigned)(c_[k] & (BNODES - 1));
            int sp = atomicAdd(&lcur[b], 1);
            stage[sp] = make_uint2((unsigned)r_[k] | (rem << 20), __float_as_uint(w_[k]));
            sbuck[sp] = (unsigned short)b;
        }
    }
    __syncthreads();
    int nE = E - base;
    if (nE > CHUNK) nE = CHUNK;
    for (int j = tid; j < nE; j += 256) {
        uint2 v = stage[j];
        u64 pv = (u64)v.x | ((u64)v.y << 32);
        __builtin_nontemporal_store(pv, (u64*)&edata[lh[sbuck[j]] + j]);
    }
}

// sliced degree: dg[rem] partial in LDS, one global atomic per node per slice
__global__ __launch_bounds__(256) void k_deg(const int* __restrict__ gBase,
                                             const uint2* __restrict__ edata,
                                             float* __restrict__ deg, int N) {
    __shared__ float dg[BNODES];
    const int tid = threadIdx.x;
    if (tid < BNODES) dg[tid] = 0.f;
    __syncthreads();
    const int b = blockIdx.x;
    const int s = gBase[b], e = gBase[b + 1];
    for (int i = s + blockIdx.y * 256 + tid; i < e; i += 512) {
        u64 v = nt_load_u64(&edata[i]);
        atomicAdd(&dg[(unsigned)v >> 20], __uint_as_float((unsigned)(v >> 32)));
    }
    __syncthreads();
    int node = (b << BSH) + tid;
    if (tid < BNODES && node < N && dg[tid] != 0.f)
        atomicAdd(&deg[node], dg[tid]);
}

// h~ = rsqrt(deg+1) * (x @ W1) stored as bf16; also stores dinv (fp32).
__global__ __launch_bounds__(256) void k_h1(const float* __restrict__ x,
                                            const float* __restrict__ W1,
                                            const float* __restrict__ deg,
                                            float* __restrict__ dinv,
                                            __hip_bfloat16* __restrict__ hdb) {
    __shared__ float Ws[128 * DH];
    __shared__ float xs[16 * 132];
    const int t = threadIdx.x;
    const int node0 = blockIdx.x * 16;
    #pragma unroll
    for (int i = 0; i < 8; ++i) Ws[t + 256 * i] = W1[t + 256 * i];
    const float4* xg = (const float4*)(x + (size_t)node0 * 128);
    #pragma unroll
    for (int it = 0; it < 2; ++it) {
        int idx = t + 256 * it;
        int n = idx >> 5, k4 = idx & 31;
        float4 v = xg[n * 32 + k4];   // x is streaming; L2 pollution here is pre-gather, ok
        *(float4*)(&xs[n * 132 + k4 * 4]) = v;
    }
    __syncthreads();
    const int node = t >> 4, feat = t & 15;
    const float* xr = &xs[node * 132];
    float acc = 0.f;
    #pragma unroll 8
    for (int k = 0; k < 128; ++k) acc += xr[k] * Ws[k * DH + feat];
    const int v = node0 + node;
    const float di = rsqrtf(deg[v] + 1.0f);
    if (feat == 0) dinv[v] = di;
    hdb[(size_t)v * DH + feat] = __float2bfloat16(di * acc);
}

// sliced layer-1 gather: 16 groups x 16 feats, unroll x8, nt edata loads;
// acc[rem][f] += w * h~[r][f] (h~ bf16, L2-resident); nt partial strip out.
__global__ __launch_bounds__(256) void k_gather1(
    const int* __restrict__ gBase, const uint2* __restrict__ edata,
    const __hip_bfloat16* __restrict__ hdb, float* __restrict__ partial) {
    __shared__ float acc[BNODES][DH + 1];
    const int tid = threadIdx.x;
    for (int i = tid; i < BNODES * (DH + 1); i += 256) ((float*)acc)[i] = 0.f;
    __syncthreads();
    const int b = blockIdx.x, sl = blockIdx.y;
    const int s = gBase[b], e = gBase[b + 1];
    const int g = tid >> 4, f = tid & 15;
    for (int i0 = s + sl * 16 + g; i0 < e; i0 += 512) {
        unsigned rx[8];
        float w[8];
        #pragma unroll
        for (int j = 0; j < 8; ++j) {
            int idx = i0 + 64 * j;
            u64 v = (idx < e) ? nt_load_u64(&edata[idx]) : 0ull;  // dummy: w=0 -> +0 to acc[0]
            rx[j] = (unsigned)v;
            w[j] = __uint_as_float((unsigned)(v >> 32));
        }
        #pragma unroll
        for (int j = 0; j < 8; ++j) {
            float hv = __bfloat162float(hdb[(size_t)(rx[j] & 0xFFFFF) * DH + f]);
            atomicAdd(&acc[rx[j] >> 20][f], w[j] * hv);
        }
    }
    __syncthreads();
    float* ps = partial + ((size_t)b * NSLICE + sl) * (DH * BNODES);
    for (int i = tid; i < DH * BNODES; i += 256)
        __builtin_nontemporal_store(acc[i >> 4][i & 15], ps + i);
}

// reduce slices + self-loop + bias + relu + dot(W2) -> q (bf16) ; init out
__global__ __launch_bounds__(256) void k_fin1(
    const float* __restrict__ partial, const float* __restrict__ dinv,
    const __hip_bfloat16* __restrict__ hdb, const float* __restrict__ b1,
    const float* __restrict__ W2, const float* __restrict__ b2,
    __hip_bfloat16* __restrict__ qb, float* __restrict__ out, int N) {
    __shared__ float acc[BNODES][DH + 1];
    __shared__ float b1s[DH], W2s[DH];
    const int tid = threadIdx.x;
    if (tid < DH) { b1s[tid] = b1[tid]; W2s[tid] = W2[tid]; }
    const int b = blockIdx.x;
    const float* ps = partial + (size_t)b * NSLICE * (DH * BNODES);
    for (int i = tid; i < DH * BNODES; i += 256) {
        float s = 0.f;
        #pragma unroll
        for (int sl = 0; sl < NSLICE; ++sl)
            s += __builtin_nontemporal_load(ps + sl * (DH * BNODES) + i);
        acc[i >> 4][i & 15] = s;
    }
    __syncthreads();
    int node = (b << BSH) + tid;
    if (tid < BNODES && node < N) {
        float dc = dinv[node];
        const __hip_bfloat16* hs = hdb + (size_t)node * DH;
        float t = 0.f;
        #pragma unroll
        for (int f = 0; f < DH; ++f) {
            float hv = __bfloat162float(hs[f]);
            t += fmaxf(dc * (acc[tid][f] + hv) + b1s[f], 0.f) * W2s[f];
        }
        float qq = dc * t;
        qb[node] = __float2bfloat16(qq);
        out[node] = b2[0] + dc * qq;    // bias + self-loop term of layer 2
    }
}

// sliced layer-2: a2[rem] += w*q[r] (q bf16, L2-resident, nt edata);
// out[node] += dinv*a2 (1 global atomic per node per slice)
__global__ __launch_bounds__(256) void k_gather2(
    const int* __restrict__ gBase, const uint2* __restrict__ edata,
    const float* __restrict__ dinv, const __hip_bfloat16* __restrict__ qb,
    float* __restrict__ out, int N) {
    __shared__ float a2[BNODES];
    const int tid = threadIdx.x;
    if (tid < BNODES) a2[tid] = 0.f;
    __syncthreads();
    const int b = blockIdx.x;
    const int s = gBase[b], e = gBase[b + 1];
    for (int i = s + blockIdx.y * 256 + tid; i < e; i += 1024) {
        u64 v0 = nt_load_u64(&edata[i]);
        int i1 = i + 512;
        u64 v1 = (i1 < e) ? nt_load_u64(&edata[i1]) : 0ull;
        float q0 = __bfloat162float(qb[(unsigned)v0 & 0xFFFFF]);
        float q1 = __bfloat162float(qb[(unsigned)v1 & 0xFFFFF]);
        atomicAdd(&a2[(unsigned)v0 >> 20], __uint_as_float((unsigned)(v0 >> 32)) * q0);
        atomicAdd(&a2[(unsigned)v1 >> 20], __uint_as_float((unsigned)(v1 >> 32)) * q1);
    }
    __syncthreads();
    int node = (b << BSH) + tid;
    if (tid < BNODES && node < N && a2[tid] != 0.f)
        atomicAdd(&out[node], dinv[node] * a2[tid]);
}

extern "C" void kernel_launch(void* const* d_in, const int* in_sizes, int n_in,
                              void* d_out, int out_size, void* d_ws, size_t ws_size,
                              hipStream_t stream) {
    const float* x  = (const float*)d_in[0];
    const int*   ei = (const int*)d_in[1];
    const float* ew = (const float*)d_in[2];
    const float* W1 = (const float*)d_in[3];
    const float* b1 = (const float*)d_in[4];
    const float* W2 = (const float*)d_in[5];
    const float* b2 = (const float*)d_in[6];
    float* out = (float*)d_out;

    const int N = in_sizes[0] / 128;       // 100000
    const int E = in_sizes[2];             // 3200000
    const int* row = ei;
    const int* col = ei + E;
    const int NB = (N + BNODES - 1) >> BSH;   // 1563
    const int NBp = (NB + 3) & ~3;

    int* gCnt    = (int*)d_ws;                 // NBp
    float* deg   = (float*)(gCnt + NBp);       // N (memset with gCnt)
    int* gBase   = (int*)(deg + N);            // NBp (uses NB+1)
    int* gCursor = gBase + NBp;                // NBp
    float* dinv  = (float*)(gCursor + NBp);    // N
    __hip_bfloat16* hdb = (__hip_bfloat16*)(dinv + N);   // 16N bf16 = 3.2 MB
    __hip_bfloat16* qb  = hdb + (size_t)16 * N;          // N bf16
    uintptr_t pp = (uintptr_t)(qb + N);
    pp = (pp + 15) & ~(uintptr_t)15;
    float* partial = (float*)pp;               // NB*NSLICE*1024 floats = 25.6 MB
    uintptr_t ep = (uintptr_t)(partial + (size_t)NB * NSLICE * (DH * BNODES));
    ep = (ep + 15) & ~(uintptr_t)15;
    uint2* edata = (uint2*)ep;                 // E

    const int hblocks = (E + HCHUNK - 1) / HCHUNK;  // 391
    const int sblocks = (E + CHUNK - 1) / CHUNK;    // 782

    hipMemsetAsync(gCnt, 0, ((size_t)NBp + N) * sizeof(int), stream);
    k_Ahist<<<hblocks, 256, 0, stream>>>(col, gCnt, E, NB);
    k_Ascan<<<1, 1024, 0, stream>>>(gCnt, gBase, gCursor, NB, E);
    k_Ascatter<<<sblocks, 256, 0, stream>>>(row, col, ew, gCursor, edata, E, NB);
    k_deg<<<dim3(NB, 2), 256, 0, stream>>>(gBase, edata, deg, N);
    k_h1<<<N / 16, 256, 0, stream>>>(x, W1, deg, dinv, hdb);
    k_gather1<<<dim3(NB, NSLICE), 256, 0, stream>>>(gBase, edata, hdb, partial);
    k_fin1<<<NB, 256, 0, stream>>>(partial, dinv, hdb, b1, W2, b2, qb, out, N);
    k_gather2<<<dim3(NB, 2), 256, 0, stream>>>(gBase, edata, dinv, qb, out, N);
}

// Round 9
// 532.884 us; speedup vs baseline: 1.0627x; 1.0627x over previous
//
#include <hip/hip_runtime.h>
#include <hip/hip_bf16.h>

// SectorGCN R9: R7 structure + per-XCD REPLICATION of the randomly-gathered
// tables. hdb (bf16 h~, 3.2MB) and qb (bf16 q, 200KB) are stored 8x; each
// gather block reads copy (linear_block_id & 7). With round-robin block->XCD
// dispatch, every random row read is a same-XCD L2 hit -> no fabric requests
// (the ~280us wall of R4-R8 was the chip's remote small-request rate at
// E=3.2M requests/pass). Correct for ANY block->XCD mapping.
// N=100000, E=3200000, d_in=128, d_h=16.

#define DH 16
#define BSH 6
#define BNODES 64
#define NB_MAX 1568
#define CHUNK 4096        // scatter chunk
#define HCHUNK 8192       // hist chunk
#define NSLICE 4
#define REP 8             // one copy per XCD

__global__ __launch_bounds__(256) void k_Ahist(const int* __restrict__ col,
                                               int* __restrict__ gCnt, int E, int NB) {
    __shared__ int lh[NB_MAX];
    const int tid = threadIdx.x;
    for (int i = tid; i < NB; i += 256) lh[i] = 0;
    __syncthreads();
    const int base = blockIdx.x * HCHUNK;
    #pragma unroll
    for (int k = 0; k < 32; ++k) {
        int e = base + tid + 256 * k;
        if (e < E) atomicAdd(&lh[col[e] >> BSH], 1);
    }
    __syncthreads();
    for (int i = tid; i < NB; i += 256) {
        int v = lh[i];
        if (v) atomicAdd(&gCnt[i], v);
    }
}

// exclusive scan of gCnt[NB], NB <= 2048 (2 elems/thread)
__global__ __launch_bounds__(1024) void k_Ascan(const int* __restrict__ gCnt,
                                                int* __restrict__ gBase,
                                                int* __restrict__ gCursor,
                                                int NB, int E) {
    __shared__ int s[1024];
    const int t = threadIdx.x;
    const int i0 = 2 * t, i1 = 2 * t + 1;
    int a = (i0 < NB) ? gCnt[i0] : 0;
    int b = (i1 < NB) ? gCnt[i1] : 0;
    int v = a + b;
    s[t] = v;
    __syncthreads();
    for (int off = 1; off < 1024; off <<= 1) {
        int u = (t >= off) ? s[t - off] : 0;
        __syncthreads();
        s[t] += u;
        __syncthreads();
    }
    int ex = s[t] - v;
    if (i0 < NB) { gBase[i0] = ex;     gCursor[i0] = ex; }
    if (i1 < NB) { gBase[i1] = ex + a; gCursor[i1] = ex + a; }
    if (t == 0) gBase[NB] = E;
}

// LDS-staged scatter: count -> local scan -> per-(block,bucket) run
// reservation -> place sorted in LDS -> linear (coalesced-run) write-out.
__global__ __launch_bounds__(256) void k_Ascatter(const int* __restrict__ row,
                                                  const int* __restrict__ col,
                                                  const float* __restrict__ ew,
                                                  int* __restrict__ gCursor,
                                                  uint2* __restrict__ edata,
                                                  int E, int NB) {
    __shared__ int lh[NB_MAX];      // counts, then (globalRun - localBase)
    __shared__ int lbase[NB_MAX];
    __shared__ int lcur[NB_MAX];
    __shared__ int tsum[256];
    __shared__ unsigned short sbuck[CHUNK];
    __shared__ uint2 stage[CHUNK];  // 32 KB
    const int tid = threadIdx.x;
    for (int i = tid; i < NB; i += 256) lh[i] = 0;
    __syncthreads();
    const int base = blockIdx.x * CHUNK;
    int r_[16], c_[16];
    float w_[16];
    #pragma unroll
    for (int k = 0; k < 16; ++k) {
        int e = base + tid + 256 * k;
        bool ok = e < E;
        c_[k] = ok ? col[e] : -1;
        r_[k] = ok ? row[e] : 0;
        w_[k] = ok ? ew[e] : 0.f;
        if (ok) atomicAdd(&lh[c_[k] >> BSH], 1);
    }
    __syncthreads();
    const int t0 = tid * 8;
    int c8[8];
    int mysum = 0;
    #pragma unroll
    for (int k = 0; k < 8; ++k) {
        c8[k] = (t0 + k < NB) ? lh[t0 + k] : 0;
        mysum += c8[k];
    }
    tsum[tid] = mysum;
    __syncthreads();
    for (int off = 1; off < 256; off <<= 1) {
        int u = (tid >= off) ? tsum[tid - off] : 0;
        __syncthreads();
        tsum[tid] += u;
        __syncthreads();
    }
    int p = tsum[tid] - mysum;
    #pragma unroll
    for (int k = 0; k < 8; ++k) {
        if (t0 + k < NB) { lbase[t0 + k] = p; lcur[t0 + k] = p; }
        p += c8[k];
    }
    __syncthreads();
    for (int b = tid; b < NB; b += 256) {
        int cnt = lh[b];
        if (cnt) {
            int g = atomicAdd(&gCursor[b], cnt);
            lh[b] = g - lbase[b];
        }
    }
    __syncthreads();
    #pragma unroll
    for (int k = 0; k < 16; ++k) {
        if (c_[k] >= 0) {
            int b = c_[k] >> BSH;
            unsigned rem = (unsigned)(c_[k] & (BNODES - 1));
            int sp = atomicAdd(&lcur[b], 1);
            stage[sp] = make_uint2((unsigned)r_[k] | (rem << 20), __float_as_uint(w_[k]));
            sbuck[sp] = (unsigned short)b;
        }
    }
    __syncthreads();
    int nE = E - base;
    if (nE > CHUNK) nE = CHUNK;
    for (int j = tid; j < nE; j += 256)
        edata[lh[sbuck[j]] + j] = stage[j];
}

// sliced degree: dg[rem] partial in LDS, one global atomic per node per slice
__global__ __launch_bounds__(256) void k_deg(const int* __restrict__ gBase,
                                             const uint2* __restrict__ edata,
                                             float* __restrict__ deg, int N) {
    __shared__ float dg[BNODES];
    const int tid = threadIdx.x;
    if (tid < BNODES) dg[tid] = 0.f;
    __syncthreads();
    const int b = blockIdx.x;
    const int s = gBase[b], e = gBase[b + 1];
    for (int i = s + blockIdx.y * 256 + tid; i < e; i += 512) {
        uint2 ed = edata[i];
        atomicAdd(&dg[ed.x >> 20], __uint_as_float(ed.y));
    }
    __syncthreads();
    int node = (b << BSH) + tid;
    if (tid < BNODES && node < N && dg[tid] != 0.f)
        atomicAdd(&deg[node], dg[tid]);
}

// h~ = rsqrt(deg+1) * (x @ W1) stored as bf16 in REP copies; dinv fp32.
__global__ __launch_bounds__(256) void k_h1(const float* __restrict__ x,
                                            const float* __restrict__ W1,
                                            const float* __restrict__ deg,
                                            float* __restrict__ dinv,
                                            __hip_bfloat16* __restrict__ hdb,
                                            int N) {
    __shared__ float Ws[128 * DH];
    __shared__ float xs[16 * 132];
    const int t = threadIdx.x;
    const int node0 = blockIdx.x * 16;
    #pragma unroll
    for (int i = 0; i < 8; ++i) Ws[t + 256 * i] = W1[t + 256 * i];
    const float4* xg = (const float4*)(x + (size_t)node0 * 128);
    #pragma unroll
    for (int it = 0; it < 2; ++it) {
        int idx = t + 256 * it;
        int n = idx >> 5, k4 = idx & 31;
        float4 v = xg[n * 32 + k4];
        *(float4*)(&xs[n * 132 + k4 * 4]) = v;
    }
    __syncthreads();
    const int node = t >> 4, feat = t & 15;
    const float* xr = &xs[node * 132];
    float acc = 0.f;
    #pragma unroll 8
    for (int k = 0; k < 128; ++k) acc += xr[k] * Ws[k * DH + feat];
    const int v = node0 + node;
    const float di = rsqrtf(deg[v] + 1.0f);
    if (feat == 0) dinv[v] = di;
    __hip_bfloat16 hb = __float2bfloat16(di * acc);
    const size_t stride = (size_t)16 * N;
    #pragma unroll
    for (int rp = 0; rp < REP; ++rp)
        hdb[rp * stride + (size_t)v * DH + feat] = hb;
}

// sliced layer-1 gather: 16 groups x 16 feats, unroll x4;
// reads XCD-local hdb copy; acc[rem][f] += w * h~[r][f]; partial strip out.
__global__ __launch_bounds__(256) void k_gather1(
    const int* __restrict__ gBase, const uint2* __restrict__ edata,
    const __hip_bfloat16* __restrict__ hdb, float* __restrict__ partial, int N) {
    __shared__ float acc[BNODES][DH + 1];
    const int tid = threadIdx.x;
    for (int i = tid; i < BNODES * (DH + 1); i += 256) ((float*)acc)[i] = 0.f;
    __syncthreads();
    const int b = blockIdx.x, sl = blockIdx.y;
    const __hip_bfloat16* hdl = hdb + (size_t)((sl * gridDim.x + b) & (REP - 1)) * 16 * N;
    const int s = gBase[b], e = gBase[b + 1];
    const int g = tid >> 4, f = tid & 15;
    for (int i = s + sl * 16 + g; i < e; i += 256) {
        uint2 e0 = edata[i];
        uint2 e1 = (i + 64  < e) ? edata[i + 64]  : make_uint2(0u, 0u);
        uint2 e2 = (i + 128 < e) ? edata[i + 128] : make_uint2(0u, 0u);
        uint2 e3 = (i + 192 < e) ? edata[i + 192] : make_uint2(0u, 0u);
        float h0 = __bfloat162float(hdl[(size_t)(e0.x & 0xFFFFF) * DH + f]);
        float h1 = __bfloat162float(hdl[(size_t)(e1.x & 0xFFFFF) * DH + f]);
        float h2 = __bfloat162float(hdl[(size_t)(e2.x & 0xFFFFF) * DH + f]);
        float h3 = __bfloat162float(hdl[(size_t)(e3.x & 0xFFFFF) * DH + f]);
        atomicAdd(&acc[e0.x >> 20][f], __uint_as_float(e0.y) * h0);
        atomicAdd(&acc[e1.x >> 20][f], __uint_as_float(e1.y) * h1);
        atomicAdd(&acc[e2.x >> 20][f], __uint_as_float(e2.y) * h2);
        atomicAdd(&acc[e3.x >> 20][f], __uint_as_float(e3.y) * h3);
    }
    __syncthreads();
    float* ps = partial + ((size_t)b * NSLICE + sl) * (DH * BNODES);
    for (int i = tid; i < DH * BNODES; i += 256)
        ps[i] = acc[i >> 4][i & 15];
}

// reduce slices + self-loop + bias + relu + dot(W2) -> q (bf16, REP copies);
// init out with bias + layer-2 self-loop term.
__global__ __launch_bounds__(256) void k_fin1(
    const float* __restrict__ partial, const float* __restrict__ dinv,
    const __hip_bfloat16* __restrict__ hdb, const float* __restrict__ b1,
    const float* __restrict__ W2, const float* __restrict__ b2,
    __hip_bfloat16* __restrict__ qb, float* __restrict__ out, int N) {
    __shared__ float acc[BNODES][DH + 1];
    __shared__ float b1s[DH], W2s[DH];
    const int tid = threadIdx.x;
    if (tid < DH) { b1s[tid] = b1[tid]; W2s[tid] = W2[tid]; }
    const int b = blockIdx.x;
    const __hip_bfloat16* hdl = hdb + (size_t)(b & (REP - 1)) * 16 * N;
    const float* ps = partial + (size_t)b * NSLICE * (DH * BNODES);
    for (int i = tid; i < DH * BNODES; i += 256) {
        float s = 0.f;
        #pragma unroll
        for (int sl = 0; sl < NSLICE; ++sl) s += ps[sl * (DH * BNODES) + i];
        acc[i >> 4][i & 15] = s;
    }
    __syncthreads();
    int node = (b << BSH) + tid;
    if (tid < BNODES && node < N) {
        float dc = dinv[node];
        const __hip_bfloat16* hs = hdl + (size_t)node * DH;
        float t = 0.f;
        #pragma unroll
        for (int f = 0; f < DH; ++f) {
            float hv = __bfloat162float(hs[f]);
            t += fmaxf(dc * (acc[tid][f] + hv) + b1s[f], 0.f) * W2s[f];
        }
        float qq = dc * t;
        __hip_bfloat16 qv = __float2bfloat16(qq);
        #pragma unroll
        for (int rp = 0; rp < REP; ++rp) qb[rp * (size_t)N + node] = qv;
        out[node] = b2[0] + dc * qq;    // bias + self-loop term of layer 2
    }
}

// sliced layer-2: a2[rem] += w*q[r] (XCD-local qb copy);
// out[node] += dinv*a2 (1 global atomic per node per slice)
__global__ __launch_bounds__(256) void k_gather2(
    const int* __restrict__ gBase, const uint2* __restrict__ edata,
    const float* __restrict__ dinv, const __hip_bfloat16* __restrict__ qb,
    float* __restrict__ out, int N) {
    __shared__ float a2[BNODES];
    const int tid = threadIdx.x;
    if (tid < BNODES) a2[tid] = 0.f;
    __syncthreads();
    const int b = blockIdx.x;
    const __hip_bfloat16* ql = qb + (size_t)((blockIdx.y * gridDim.x + b) & (REP - 1)) * N;
    const int s = gBase[b], e = gBase[b + 1];
    for (int i = s + blockIdx.y * 256 + tid; i < e; i += 512) {
        uint2 ed = edata[i];
        float qv = __bfloat162float(ql[ed.x & 0xFFFFF]);
        atomicAdd(&a2[ed.x >> 20], __uint_as_float(ed.y) * qv);
    }
    __syncthreads();
    int node = (b << BSH) + tid;
    if (tid < BNODES && node < N && a2[tid] != 0.f)
        atomicAdd(&out[node], dinv[node] * a2[tid]);
}

extern "C" void kernel_launch(void* const* d_in, const int* in_sizes, int n_in,
                              void* d_out, int out_size, void* d_ws, size_t ws_size,
                              hipStream_t stream) {
    const float* x  = (const float*)d_in[0];
    const int*   ei = (const int*)d_in[1];
    const float* ew = (const float*)d_in[2];
    const float* W1 = (const float*)d_in[3];
    const float* b1 = (const float*)d_in[4];
    const float* W2 = (const float*)d_in[5];
    const float* b2 = (const float*)d_in[6];
    float* out = (float*)d_out;

    const int N = in_sizes[0] / 128;       // 100000
    const int E = in_sizes[2];             // 3200000
    const int* row = ei;
    const int* col = ei + E;
    const int NB = (N + BNODES - 1) >> BSH;   // 1563
    const int NBp = (NB + 3) & ~3;

    int* gCnt    = (int*)d_ws;                 // NBp
    float* deg   = (float*)(gCnt + NBp);       // N (memset with gCnt)
    int* gBase   = (int*)(deg + N);            // NBp (uses NB+1)
    int* gCursor = gBase + NBp;                // NBp
    float* dinv  = (float*)(gCursor + NBp);    // N
    __hip_bfloat16* hdb = (__hip_bfloat16*)(dinv + N);   // REP*16N bf16 = 25.6 MB
    __hip_bfloat16* qb  = hdb + (size_t)REP * 16 * N;    // REP*N bf16 = 1.6 MB
    uintptr_t pp = (uintptr_t)(qb + (size_t)REP * N);
    pp = (pp + 15) & ~(uintptr_t)15;
    float* partial = (float*)pp;               // NB*NSLICE*1024 floats = 25.6 MB
    uintptr_t ep = (uintptr_t)(partial + (size_t)NB * NSLICE * (DH * BNODES));
    ep = (ep + 15) & ~(uintptr_t)15;
    uint2* edata = (uint2*)ep;                 // E (25.6 MB)

    const int hblocks = (E + HCHUNK - 1) / HCHUNK;  // 391
    const int sblocks = (E + CHUNK - 1) / CHUNK;    // 782

    hipMemsetAsync(gCnt, 0, ((size_t)NBp + N) * sizeof(int), stream);
    k_Ahist<<<hblocks, 256, 0, stream>>>(col, gCnt, E, NB);
    k_Ascan<<<1, 1024, 0, stream>>>(gCnt, gBase, gCursor, NB, E);
    k_Ascatter<<<sblocks, 256, 0, stream>>>(row, col, ew, gCursor, edata, E, NB);
    k_deg<<<dim3(NB, 2), 256, 0, stream>>>(gBase, edata, deg, N);
    k_h1<<<N / 16, 256, 0, stream>>>(x, W1, deg, dinv, hdb, N);
    k_gather1<<<dim3(NB, NSLICE), 256, 0, stream>>>(gBase, edata, hdb, partial, N);
    k_fin1<<<NB, 256, 0, stream>>>(partial, dinv, hdb, b1, W2, b2, qb, out, N);
    k_gather2<<<dim3(NB, 2), 256, 0, stream>>>(gBase, edata, dinv, qb, out, N);
}

// Round 10
// 529.400 us; speedup vs baseline: 1.0697x; 1.0066x over previous
//
#include <hip/hip_runtime.h>
#include <hip/hip_bf16.h>

// SectorGCN R10: R9 + de-serialized gather loops.
// Root cause of the 280us plateau (R4-R9): compiler allocated 8-16 VGPRs
// (launch_bounds(256) default) -> unrolled loads' results couldn't stay
// live -> s_waitcnt vmcnt(0) after every load -> ONE dependent chain per
// wave. Fix: branchless clamped loads (no exec-mask branches), explicit
// 2-stage software pipeline (prefetch next edata batch while current hdb
// gathers fly), __launch_bounds__(256,4) to allow ~128 VGPRs.
// N=100000, E=3200000, d_in=128, d_h=16.

#define DH 16
#define BSH 6
#define BNODES 64
#define NB_MAX 1568
#define CHUNK 4096        // scatter chunk
#define HCHUNK 8192       // hist chunk
#define NSLICE 4
#define REP 8             // hdb/qb copies (per-XCD L2 locality)

__global__ __launch_bounds__(256) void k_Ahist(const int* __restrict__ col,
                                               int* __restrict__ gCnt, int E, int NB) {
    __shared__ int lh[NB_MAX];
    const int tid = threadIdx.x;
    for (int i = tid; i < NB; i += 256) lh[i] = 0;
    __syncthreads();
    const int base = blockIdx.x * HCHUNK;
    #pragma unroll
    for (int k = 0; k < 32; ++k) {
        int e = base + tid + 256 * k;
        if (e < E) atomicAdd(&lh[col[e] >> BSH], 1);
    }
    __syncthreads();
    for (int i = tid; i < NB; i += 256) {
        int v = lh[i];
        if (v) atomicAdd(&gCnt[i], v);
    }
}

__global__ __launch_bounds__(1024) void k_Ascan(const int* __restrict__ gCnt,
                                                int* __restrict__ gBase,
                                                int* __restrict__ gCursor,
                                                int NB, int E) {
    __shared__ int s[1024];
    const int t = threadIdx.x;
    const int i0 = 2 * t, i1 = 2 * t + 1;
    int a = (i0 < NB) ? gCnt[i0] : 0;
    int b = (i1 < NB) ? gCnt[i1] : 0;
    int v = a + b;
    s[t] = v;
    __syncthreads();
    for (int off = 1; off < 1024; off <<= 1) {
        int u = (t >= off) ? s[t - off] : 0;
        __syncthreads();
        s[t] += u;
        __syncthreads();
    }
    int ex = s[t] - v;
    if (i0 < NB) { gBase[i0] = ex;     gCursor[i0] = ex; }
    if (i1 < NB) { gBase[i1] = ex + a; gCursor[i1] = ex + a; }
    if (t == 0) gBase[NB] = E;
}

__global__ __launch_bounds__(256) void k_Ascatter(const int* __restrict__ row,
                                                  const int* __restrict__ col,
                                                  const float* __restrict__ ew,
                                                  int* __restrict__ gCursor,
                                                  uint2* __restrict__ edata,
                                                  int E, int NB) {
    __shared__ int lh[NB_MAX];
    __shared__ int lbase[NB_MAX];
    __shared__ int lcur[NB_MAX];
    __shared__ int tsum[256];
    __shared__ unsigned short sbuck[CHUNK];
    __shared__ uint2 stage[CHUNK];
    const int tid = threadIdx.x;
    for (int i = tid; i < NB; i += 256) lh[i] = 0;
    __syncthreads();
    const int base = blockIdx.x * CHUNK;
    int r_[16], c_[16];
    float w_[16];
    #pragma unroll
    for (int k = 0; k < 16; ++k) {
        int e = base + tid + 256 * k;
        bool ok = e < E;
        c_[k] = ok ? col[e] : -1;
        r_[k] = ok ? row[e] : 0;
        w_[k] = ok ? ew[e] : 0.f;
        if (ok) atomicAdd(&lh[c_[k] >> BSH], 1);
    }
    __syncthreads();
    const int t0 = tid * 8;
    int c8[8];
    int mysum = 0;
    #pragma unroll
    for (int k = 0; k < 8; ++k) {
        c8[k] = (t0 + k < NB) ? lh[t0 + k] : 0;
        mysum += c8[k];
    }
    tsum[tid] = mysum;
    __syncthreads();
    for (int off = 1; off < 256; off <<= 1) {
        int u = (tid >= off) ? tsum[tid - off] : 0;
        __syncthreads();
        tsum[tid] += u;
        __syncthreads();
    }
    int p = tsum[tid] - mysum;
    #pragma unroll
    for (int k = 0; k < 8; ++k) {
        if (t0 + k < NB) { lbase[t0 + k] = p; lcur[t0 + k] = p; }
        p += c8[k];
    }
    __syncthreads();
    for (int b = tid; b < NB; b += 256) {
        int cnt = lh[b];
        if (cnt) {
            int g = atomicAdd(&gCursor[b], cnt);
            lh[b] = g - lbase[b];
        }
    }
    __syncthreads();
    #pragma unroll
    for (int k = 0; k < 16; ++k) {
        if (c_[k] >= 0) {
            int b = c_[k] >> BSH;
            unsigned rem = (unsigned)(c_[k] & (BNODES - 1));
            int sp = atomicAdd(&lcur[b], 1);
            stage[sp] = make_uint2((unsigned)r_[k] | (rem << 20), __float_as_uint(w_[k]));
            sbuck[sp] = (unsigned short)b;
        }
    }
    __syncthreads();
    int nE = E - base;
    if (nE > CHUNK) nE = CHUNK;
    for (int j = tid; j < nE; j += 256)
        edata[lh[sbuck[j]] + j] = stage[j];
}

// sliced degree, pipelined lane-per-edge, branchless clamped loads.
__global__ __launch_bounds__(256, 4) void k_deg(const int* __restrict__ gBase,
                                                const uint2* __restrict__ edata,
                                                float* __restrict__ deg, int N) {
    __shared__ float dg[BNODES];
    const int tid = threadIdx.x;
    if (tid < BNODES) dg[tid] = 0.f;
    __syncthreads();
    const int b = blockIdx.x;
    const int s = gBase[b], e = gBase[b + 1];
    int i = s + blockIdx.y * 256 + tid;
    if (i < e + 512) {   // uniform-ish guard; inner fully branchless
        int ci = (i < e) ? i : s;
        uint2 cur = edata[ci];
        for (; i < e; ) {
            int inext = i + 512;
            int cn = (inext < e) ? inext : s;
            uint2 nxt = edata[cn];
            float w = (i < e) ? __uint_as_float(cur.y) : 0.f;
            atomicAdd(&dg[cur.x >> 20], w);
            cur = nxt;
            i = inext;
        }
    }
    __syncthreads();
    int node = (b << BSH) + tid;
    if (tid < BNODES && node < N && dg[tid] != 0.f)
        atomicAdd(&deg[node], dg[tid]);
}

// h~ = rsqrt(deg+1) * (x @ W1) stored bf16 in REP copies; dinv fp32.
__global__ __launch_bounds__(256) void k_h1(const float* __restrict__ x,
                                            const float* __restrict__ W1,
                                            const float* __restrict__ deg,
                                            float* __restrict__ dinv,
                                            __hip_bfloat16* __restrict__ hdb,
                                            int N) {
    __shared__ float Ws[128 * DH];
    __shared__ float xs[16 * 132];
    const int t = threadIdx.x;
    const int node0 = blockIdx.x * 16;
    #pragma unroll
    for (int i = 0; i < 8; ++i) Ws[t + 256 * i] = W1[t + 256 * i];
    const float4* xg = (const float4*)(x + (size_t)node0 * 128);
    #pragma unroll
    for (int it = 0; it < 2; ++it) {
        int idx = t + 256 * it;
        int n = idx >> 5, k4 = idx & 31;
        float4 v = xg[n * 32 + k4];
        *(float4*)(&xs[n * 132 + k4 * 4]) = v;
    }
    __syncthreads();
    const int node = t >> 4, feat = t & 15;
    const float* xr = &xs[node * 132];
    float acc = 0.f;
    #pragma unroll 8
    for (int k = 0; k < 128; ++k) acc += xr[k] * Ws[k * DH + feat];
    const int v = node0 + node;
    const float di = rsqrtf(deg[v] + 1.0f);
    if (feat == 0) dinv[v] = di;
    __hip_bfloat16 hb = __float2bfloat16(di * acc);
    const size_t stride = (size_t)16 * N;
    #pragma unroll
    for (int rp = 0; rp < REP; ++rp)
        hdb[rp * stride + (size_t)v * DH + feat] = hb;
}

// sliced layer-1 gather, software-pipelined:
//  stage A: 4 edata words (next iter) prefetch
//  stage B: 4 hdb row-gathers (current iter) + 4 LDS atomics
// branchless clamped addressing; w masked to 0 beyond bucket end.
__global__ __launch_bounds__(256, 4) void k_gather1(
    const int* __restrict__ gBase, const uint2* __restrict__ edata,
    const __hip_bfloat16* __restrict__ hdb, float* __restrict__ partial, int N) {
    __shared__ float acc[BNODES][DH + 1];
    const int tid = threadIdx.x;
    for (int i = tid; i < BNODES * (DH + 1); i += 256) ((float*)acc)[i] = 0.f;
    __syncthreads();
    const int b = blockIdx.x, sl = blockIdx.y;
    const __hip_bfloat16* hdl = hdb + (size_t)((sl * gridDim.x + b) & (REP - 1)) * 16 * N;
    const int s = gBase[b], e = gBase[b + 1];
    const int g = tid >> 4, f = tid & 15;

    int i = s + sl * 16 + g;
    uint2 cur0, cur1, cur2, cur3;
    {   // prologue: clamped unconditional loads
        int i0 = i, i1 = i + 64, i2 = i + 128, i3 = i + 192;
        cur0 = edata[(i0 < e) ? i0 : s];
        cur1 = edata[(i1 < e) ? i1 : s];
        cur2 = edata[(i2 < e) ? i2 : s];
        cur3 = edata[(i3 < e) ? i3 : s];
    }
    for (; i < e; ) {
        const int inext = i + 256;
        // prefetch next batch (clamped; discarded after last iter)
        int n0 = inext, n1 = inext + 64, n2 = inext + 128, n3 = inext + 192;
        uint2 x0 = edata[(n0 < e) ? n0 : s];
        uint2 x1 = edata[(n1 < e) ? n1 : s];
        uint2 x2 = edata[(n2 < e) ? n2 : s];
        uint2 x3 = edata[(n3 < e) ? n3 : s];
        // current batch: mask weights, gather rows, accumulate
        float w0 = (i       < e) ? __uint_as_float(cur0.y) : 0.f;
        float w1 = (i + 64  < e) ? __uint_as_float(cur1.y) : 0.f;
        float w2 = (i + 128 < e) ? __uint_as_float(cur2.y) : 0.f;
        float w3 = (i + 192 < e) ? __uint_as_float(cur3.y) : 0.f;
        float h0 = __bfloat162float(hdl[(size_t)(cur0.x & 0xFFFFF) * DH + f]);
        float h1 = __bfloat162float(hdl[(size_t)(cur1.x & 0xFFFFF) * DH + f]);
        float h2 = __bfloat162float(hdl[(size_t)(cur2.x & 0xFFFFF) * DH + f]);
        float h3 = __bfloat162float(hdl[(size_t)(cur3.x & 0xFFFFF) * DH + f]);
        atomicAdd(&acc[cur0.x >> 20][f], w0 * h0);
        atomicAdd(&acc[cur1.x >> 20][f], w1 * h1);
        atomicAdd(&acc[cur2.x >> 20][f], w2 * h2);
        atomicAdd(&acc[cur3.x >> 20][f], w3 * h3);
        cur0 = x0; cur1 = x1; cur2 = x2; cur3 = x3;
        i = inext;
    }
    __syncthreads();
    float* ps = partial + ((size_t)b * NSLICE + sl) * (DH * BNODES);
    for (int j = tid; j < DH * BNODES; j += 256)
        ps[j] = acc[j >> 4][j & 15];
}

// reduce slices + self-loop + bias + relu + dot(W2) -> q (bf16, REP copies);
// init out with bias + layer-2 self-loop term.
__global__ __launch_bounds__(256) void k_fin1(
    const float* __restrict__ partial, const float* __restrict__ dinv,
    const __hip_bfloat16* __restrict__ hdb, const float* __restrict__ b1,
    const float* __restrict__ W2, const float* __restrict__ b2,
    __hip_bfloat16* __restrict__ qb, float* __restrict__ out, int N) {
    __shared__ float acc[BNODES][DH + 1];
    __shared__ float b1s[DH], W2s[DH];
    const int tid = threadIdx.x;
    if (tid < DH) { b1s[tid] = b1[tid]; W2s[tid] = W2[tid]; }
    const int b = blockIdx.x;
    const __hip_bfloat16* hdl = hdb + (size_t)(b & (REP - 1)) * 16 * N;
    const float* ps = partial + (size_t)b * NSLICE * (DH * BNODES);
    for (int i = tid; i < DH * BNODES; i += 256) {
        float s = 0.f;
        #pragma unroll
        for (int sl = 0; sl < NSLICE; ++sl) s += ps[sl * (DH * BNODES) + i];
        acc[i >> 4][i & 15] = s;
    }
    __syncthreads();
    int node = (b << BSH) + tid;
    if (tid < BNODES && node < N) {
        float dc = dinv[node];
        const __hip_bfloat16* hs = hdl + (size_t)node * DH;
        float t = 0.f;
        #pragma unroll
        for (int f = 0; f < DH; ++f) {
            float hv = __bfloat162float(hs[f]);
            t += fmaxf(dc * (acc[tid][f] + hv) + b1s[f], 0.f) * W2s[f];
        }
        float qq = dc * t;
        __hip_bfloat16 qv = __float2bfloat16(qq);
        #pragma unroll
        for (int rp = 0; rp < REP; ++rp) qb[rp * (size_t)N + node] = qv;
        out[node] = b2[0] + dc * qq;
    }
}

// sliced layer-2, pipelined lane-per-edge: a2[rem] += w*q[r]; then
// out[node] += dinv*a2 (1 global atomic per node per slice)
__global__ __launch_bounds__(256, 4) void k_gather2(
    const int* __restrict__ gBase, const uint2* __restrict__ edata,
    const float* __restrict__ dinv, const __hip_bfloat16* __restrict__ qb,
    float* __restrict__ out, int N) {
    __shared__ float a2[BNODES];
    const int tid = threadIdx.x;
    if (tid < BNODES) a2[tid] = 0.f;
    __syncthreads();
    const int b = blockIdx.x;
    const __hip_bfloat16* ql = qb + (size_t)((blockIdx.y * gridDim.x + b) & (REP - 1)) * N;
    const int s = gBase[b], e = gBase[b + 1];
    int i = s + blockIdx.y * 256 + tid;
    if (i < e + 512) {
        int ci = (i < e) ? i : s;
        uint2 cur = edata[ci];
        for (; i < e; ) {
            int inext = i + 512;
            uint2 nxt = edata[(inext < e) ? inext : s];
            float w = (i < e) ? __uint_as_float(cur.y) : 0.f;
            float qv = __bfloat162float(ql[cur.x & 0xFFFFF]);
            atomicAdd(&a2[cur.x >> 20], w * qv);
            cur = nxt;
            i = inext;
        }
    }
    __syncthreads();
    int node = (b << BSH) + tid;
    if (tid < BNODES && node < N && a2[tid] != 0.f)
        atomicAdd(&out[node], dinv[node] * a2[tid]);
}

extern "C" void kernel_launch(void* const* d_in, const int* in_sizes, int n_in,
                              void* d_out, int out_size, void* d_ws, size_t ws_size,
                              hipStream_t stream) {
    const float* x  = (const float*)d_in[0];
    const int*   ei = (const int*)d_in[1];
    const float* ew = (const float*)d_in[2];
    const float* W1 = (const float*)d_in[3];
    const float* b1 = (const float*)d_in[4];
    const float* W2 = (const float*)d_in[5];
    const float* b2 = (const float*)d_in[6];
    float* out = (float*)d_out;

    const int N = in_sizes[0] / 128;       // 100000
    const int E = in_sizes[2];             // 3200000
    const int* row = ei;
    const int* col = ei + E;
    const int NB = (N + BNODES - 1) >> BSH;   // 1563
    const int NBp = (NB + 3) & ~3;

    int* gCnt    = (int*)d_ws;                 // NBp
    float* deg   = (float*)(gCnt + NBp);       // N (memset with gCnt)
    int* gBase   = (int*)(deg + N);            // NBp (uses NB+1)
    int* gCursor = gBase + NBp;                // NBp
    float* dinv  = (float*)(gCursor + NBp);    // N
    __hip_bfloat16* hdb = (__hip_bfloat16*)(dinv + N);   // REP*16N bf16 = 25.6 MB
    __hip_bfloat16* qb  = hdb + (size_t)REP * 16 * N;    // REP*N bf16 = 1.6 MB
    uintptr_t pp = (uintptr_t)(qb + (size_t)REP * N);
    pp = (pp + 15) & ~(uintptr_t)15;
    float* partial = (float*)pp;               // NB*NSLICE*1024 floats = 25.6 MB
    uintptr_t ep = (uintptr_t)(partial + (size_t)NB * NSLICE * (DH * BNODES));
    ep = (ep + 15) & ~(uintptr_t)15;
    uint2* edata = (uint2*)ep;                 // E (25.6 MB)

    const int hblocks = (E + HCHUNK - 1) / HCHUNK;  // 391
    const int sblocks = (E + CHUNK - 1) / CHUNK;    // 782

    hipMemsetAsync(gCnt, 0, ((size_t)NBp + N) * sizeof(int), stream);
    k_Ahist<<<hblocks, 256, 0, stream>>>(col, gCnt, E, NB);
    k_Ascan<<<1, 1024, 0, stream>>>(gCnt, gBase, gCursor, NB, E);
    k_Ascatter<<<sblocks, 256, 0, stream>>>(row, col, ew, gCursor, edata, E, NB);
    k_deg<<<dim3(NB, 2), 256, 0, stream>>>(gBase, edata, deg, N);
    k_h1<<<N / 16, 256, 0, stream>>>(x, W1, deg, dinv, hdb, N);
    k_gather1<<<dim3(NB, NSLICE), 256, 0, stream>>>(gBase, edata, hdb, partial, N);
    k_fin1<<<NB, 256, 0, stream>>>(partial, dinv, hdb, b1, W2, b2, qb, out, N);
    k_gather2<<<dim3(NB, 2), 256, 0, stream>>>(gBase, edata, dinv, qb, out, N);
}